// Round 10
// baseline (166.404 us; speedup 1.0000x reference)
//
#include <hip/hip_runtime.h>

typedef __attribute__((ext_vector_type(8))) short bf16x8;
typedef __attribute__((ext_vector_type(4))) float f32x4;
typedef __attribute__((ext_vector_type(16))) float f32x16;

#define NH 8
#define CD 64
#define TLEN 1024
#define SENC 1024
#define STOT 2048
#define SK 64
#define LDS_P 72     // padded P row stride (bf16 elems); 144B rows stay 16B-aligned

// fixed softmax max (exact for any fixed M; only float range matters)
#define QSCALE 0.18033688f   // 0.125 * log2(e)
#define M2     12.98425550f  // 9.0  * log2(e)

__device__ __forceinline__ ushort f2bf(float f) {
  uint x = __builtin_bit_cast(uint, f);
  uint r = (x + 0x7fffu + ((x >> 16) & 1u)) >> 16;
  return (ushort)r;
}
__device__ __forceinline__ uint pkbf(float a, float b) {
  return (uint)f2bf(a) | ((uint)f2bf(b) << 16);
}
__device__ __forceinline__ uint4 pack8(const ushort* p) {
  uint4 u;
  u.x = (uint)p[0] | ((uint)p[1] << 16);
  u.y = (uint)p[2] | ((uint)p[3] << 16);
  u.z = (uint)p[4] | ((uint)p[5] << 16);
  u.w = (uint)p[6] | ((uint)p[7] << 16);
  return u;
}

// ---------------- pre-pass: cast K/V to bf16 in workspace (R8-verified) -----
__global__ __launch_bounds__(256)
void repack_kernel(const float* __restrict__ x, const float* __restrict__ ekv,
                   ushort* __restrict__ ktw, ushort* __restrict__ vnw) {
  const int kx = blockIdx.x;   // key tile 0..31 (64 keys each)
  const int bh = blockIdx.y;   // 0..31
  const int b = bh >> 3, h = bh & 7;
  const int t = threadIdx.x;
  const float* ks;
  const float* vs;
  if (kx < 16) {
    ks = ekv + (size_t)(b * 2 * NH * CD + h * CD) * SENC + kx * 64;
    vs = ekv + (size_t)(b * 2 * NH * CD + NH * CD + h * CD) * SENC + kx * 64;
  } else {
    ks = x + (size_t)(b * 3 * NH * CD + NH * CD + h * CD) * TLEN + (kx - 16) * 64;
    vs = x + (size_t)(b * 3 * NH * CD + 2 * NH * CD + h * CD) * TLEN + (kx - 16) * 64;
  }
  if (blockIdx.z == 0) {
    __shared__ float Lt[64 * 65];
    const int ci = t >> 2, seg = t & 3;
#pragma unroll
    for (int j = 0; j < 4; ++j) {
      float4 d = *(const float4*)&ks[ci * 1024 + seg * 16 + 4 * j];
      Lt[ci * 65 + seg * 16 + 4 * j + 0] = d.x;
      Lt[ci * 65 + seg * 16 + 4 * j + 1] = d.y;
      Lt[ci * 65 + seg * 16 + 4 * j + 2] = d.z;
      Lt[ci * 65 + seg * 16 + 4 * j + 3] = d.w;
    }
    __syncthreads();
    const int key = t >> 2;
    ushort tmp[16];
#pragma unroll
    for (int u = 0; u < 16; ++u)
      tmp[u] = f2bf(Lt[(seg * 16 + u) * 65 + key]);
    ushort* dst = ktw + ((size_t)bh * STOT + kx * 64 + key) * CD + seg * 16;
    *(uint4*)dst = pack8(tmp);
    *(uint4*)(dst + 8) = pack8(tmp + 8);
  } else {
    const int ci = t >> 2, seg = t & 3;
    ushort tmp[16];
#pragma unroll
    for (int j = 0; j < 4; ++j) {
      float4 d = *(const float4*)&vs[ci * 1024 + seg * 16 + 4 * j];
      tmp[4 * j + 0] = f2bf(d.x);
      tmp[4 * j + 1] = f2bf(d.y);
      tmp[4 * j + 2] = f2bf(d.z);
      tmp[4 * j + 3] = f2bf(d.w);
    }
    ushort* dst = vnw + (size_t)bh * CD * STOT + (size_t)ci * STOT + kx * 64 + seg * 16;
    *(uint4*)dst = pack8(tmp);
    *(uint4*)(dst + 8) = pack8(tmp + 8);
  }
}

// ---------------- main: 32x32 MFMA, no K/V staging, key-split-4 -------------
// Wave = 32 queries x 64 keys/iter. A-frags (K for S^T, V for PV) are b128
// global loads from bf16 workspace (L2-resident per XCD via swizzle). Only P
// round-trips through LDS (wave-private rows). Partial O/l accumulated with
// device atomics (fixed-max softmax makes partials directly addable).
__global__ __launch_bounds__(256, 3)
void qkv_attn_split(const float* __restrict__ x, const ushort* __restrict__ ktw,
                    const ushort* __restrict__ vnw, float* __restrict__ out,
                    float* __restrict__ pl) {
  __shared__ __align__(16) ushort Pw[4][32 * LDS_P];  // per-wave P^T[q32][key64]

  const int tid  = threadIdx.x;
  const int w    = tid >> 6;
  const int lane = tid & 63;
  const int hi   = lane >> 5;
  const int l32  = lane & 31;

  // grid decode: f = (bhHi2<<8)|(qg3,sp2<<3)|(bhLo3) -> all 32 blocks of a bh
  // land on XCD f%8 = bh&7 (K/V bf16 per bh = 512 KB stays L2-resident)
  const int f   = blockIdx.x;
  const int bh  = (f & 7) + 8 * (f >> 8);
  const int mid = (f >> 3) & 31;
  const int qg  = mid >> 2;       // 0..7 : 128-query group
  const int sp  = mid & 3;        // 0..3 : 512-key split
  const int b = bh >> 3, h = bh & 7;
  const int q0  = qg * 128 + w * 32;   // this wave's query base
  const int s0b = sp * 512;

  const float* qgp = x + (size_t)(b * 3 * NH * CD + h * CD) * TLEN;
  const ushort* ktb = ktw + (size_t)bh * STOT * CD;   // [key][ci]
  const ushort* vnb = vnw + (size_t)bh * CD * STOT;   // [ci][key]
  float* og = out + (size_t)(b * NH * CD + h * CD) * TLEN;

  // ---- Q B-frags (hoisted): B[k=ci][n=q]: lane needs Q[q0+l32][kt*16+hi*8+j]
  bf16x8 qf[4];
#pragma unroll
  for (int kt = 0; kt < 4; ++kt) {
    uint u0, u1, u2, u3;
    {
      const float* qc = qgp + (size_t)(kt * 16 + hi * 8) * TLEN + q0 + l32;
      float a0 = qc[0 * TLEN] * QSCALE, a1 = qc[1 * TLEN] * QSCALE;
      float a2 = qc[2 * TLEN] * QSCALE, a3 = qc[3 * TLEN] * QSCALE;
      float a4 = qc[4 * TLEN] * QSCALE, a5 = qc[5 * TLEN] * QSCALE;
      float a6 = qc[6 * TLEN] * QSCALE, a7 = qc[7 * TLEN] * QSCALE;
      u0 = pkbf(a0, a1); u1 = pkbf(a2, a3); u2 = pkbf(a4, a5); u3 = pkbf(a6, a7);
    }
    qf[kt] = __builtin_bit_cast(bf16x8, make_uint4(u0, u1, u2, u3));
  }

  f32x16 oa0 = {0,0,0,0,0,0,0,0,0,0,0,0,0,0,0,0};
  f32x16 oa1 = {0,0,0,0,0,0,0,0,0,0,0,0,0,0,0,0};
  float l_acc = 0.f;
  ushort* pws = &Pw[w][l32 * LDS_P];   // this lane's P row (q = l32)

  for (int it = 0; it < 8; ++it) {
    const int s0 = s0b + it * SK;

    // ---- K A-frags: A[m=key][k=ci], m = mt*32+l32, k = kt*16+hi*8+j (b128)
    bf16x8 kf[2][4];
    const ushort* kr = ktb + (size_t)(s0 + l32) * CD + hi * 8;
#pragma unroll
    for (int mt = 0; mt < 2; ++mt)
#pragma unroll
      for (int kt = 0; kt < 4; ++kt)
        kf[mt][kt] = *(const bf16x8*)(kr + (size_t)mt * 32 * CD + kt * 16);

    // ---- S^T = K * Q^T (2 key-tiles x 4 ci-ktiles)
    f32x16 st0 = {0,0,0,0,0,0,0,0,0,0,0,0,0,0,0,0};
    f32x16 st1 = {0,0,0,0,0,0,0,0,0,0,0,0,0,0,0,0};
#pragma unroll
    for (int kt = 0; kt < 4; ++kt) {
      st0 = __builtin_amdgcn_mfma_f32_32x32x16_bf16(kf[0][kt], qf[kt], st0, 0, 0, 0);
      st1 = __builtin_amdgcn_mfma_f32_32x32x16_bf16(kf[1][kt], qf[kt], st1, 0, 0, 0);
    }

    // ---- V A-frags issued early: A[m=ci][k=key] (b128 from vnb)
    bf16x8 vf[2][4];
    const ushort* vr = vnb + (size_t)l32 * STOT + s0 + hi * 8;
#pragma unroll
    for (int mt2 = 0; mt2 < 2; ++mt2)
#pragma unroll
      for (int kt2 = 0; kt2 < 4; ++kt2)
        vf[mt2][kt2] = *(const bf16x8*)(vr + (size_t)mt2 * 32 * STOT + kt2 * 16);

    // ---- fixed-max softmax + P^T write (wave-private LDS rows)
    // C layout: col=q=l32, row(key_local) = (r&3)+8*(r>>2)+4*hi (+mt*32)
#pragma unroll
    for (int mt = 0; mt < 2; ++mt) {
      const f32x16 st = mt ? st1 : st0;
      float p[16];
#pragma unroll
      for (int r = 0; r < 16; ++r) {
        p[r] = exp2f(st[r] - M2);
        l_acc += p[r];
      }
#pragma unroll
      for (int g = 0; g < 4; ++g) {
        uint lo = pkbf(p[4 * g + 0], p[4 * g + 1]);
        uint hh = pkbf(p[4 * g + 2], p[4 * g + 3]);
        *(uint2*)&pws[mt * 32 + 8 * g + 4 * hi] = make_uint2(lo, hh);
      }
    }
    __asm__ __volatile__("s_waitcnt lgkmcnt(0)" ::: "memory");

    // ---- P^T B-frags: B[k=key][n=q=l32]: read own row, k = kt2*16+hi*8+j
    bf16x8 pf[4];
#pragma unroll
    for (int kt2 = 0; kt2 < 4; ++kt2)
      pf[kt2] = *(const bf16x8*)&pws[kt2 * 16 + hi * 8];

    // ---- O^T += V * P^T
#pragma unroll
    for (int kt2 = 0; kt2 < 4; ++kt2) {
      oa0 = __builtin_amdgcn_mfma_f32_32x32x16_bf16(vf[0][kt2], pf[kt2], oa0, 0, 0, 0);
      oa1 = __builtin_amdgcn_mfma_f32_32x32x16_bf16(vf[1][kt2], pf[kt2], oa1, 0, 0, 0);
    }
  }

  // ---- epilogue: accumulate partials (fixed-max => directly addable)
  l_acc += __shfl_xor(l_acc, 32);   // combine key-halves for q = l32
  if (hi == 0) atomicAdd(&pl[bh * TLEN + q0 + l32], l_acc);
#pragma unroll
  for (int mt2 = 0; mt2 < 2; ++mt2) {
    const f32x16 oa = mt2 ? oa1 : oa0;
#pragma unroll
    for (int r = 0; r < 16; ++r) {
      int ci = mt2 * 32 + (r & 3) + 8 * (r >> 2) + 4 * hi;
      atomicAdd(&og[(size_t)ci * TLEN + q0 + l32], oa[r]);
    }
  }
}

// ---------------- finalize: out /= l ----------------------------------------
__global__ __launch_bounds__(256)
void finalize_kernel(float* __restrict__ out, const float* __restrict__ pl) {
  int i = blockIdx.x * 256 + threadIdx.x;      // float4 index, 524288 total
  float4 v = ((const float4*)out)[i];
  int flat = i * 4;
  int bh = flat >> 16;                         // 64*1024 floats per bh
  int t  = flat & 1023;
  const float4 lv = *(const float4*)&pl[bh * 1024 + t];
  v.x /= lv.x; v.y /= lv.y; v.z /= lv.z; v.w /= lv.w;
  ((float4*)out)[i] = v;
}

// ---------------- R9 fallback (verified) for small workspace ----------------
#define BQ 64
#define NIT (STOT / SK)
__global__ __launch_bounds__(256, 3)
void qkv_attn_ws(const float* __restrict__ x, const ushort* __restrict__ ktw,
                 const ushort* __restrict__ vnw, float* __restrict__ out) {
  __shared__ __align__(16) ushort Kb[2][SK * LDS_P];
  __shared__ __align__(16) ushort Vb[2][CD * LDS_P];
  __shared__ __align__(16) ushort Pw[4 * 16 * LDS_P];
  const int tid = threadIdx.x, w = tid >> 6, lane = tid & 63;
  const int quad = lane >> 4, l16 = lane & 15;
  const int f = blockIdx.x;
  const int bh = (f & 7) + 8 * (f >> 7);
  const int qt = (f >> 3) & 15;
  const int b = bh >> 3, h = bh & 7, t0 = qt * BQ;
  const float* qg = x + (size_t)(b * 3 * NH * CD + h * CD) * TLEN;
  float* og = out + (size_t)(b * NH * CD + h * CD) * TLEN;
  const ushort* ktb = ktw + (size_t)bh * STOT * CD;
  const ushort* vnb = vnw + (size_t)bh * CD * STOT;
#pragma unroll
  for (int e = 0; e < 16; ++e) {
    int ci = 4 * e + w;
    Kb[1][lane * LDS_P + ci] = f2bf(qg[ci * TLEN + t0 + lane] * QSCALE);
  }
  __syncthreads();
  bf16x8 qfrag[2];
#pragma unroll
  for (int kst = 0; kst < 2; ++kst)
    qfrag[kst] = *(const bf16x8*)&Kb[1][(w * 16 + l16) * LDS_P + kst * 32 + quad * 8];
  const int row = tid >> 2, seg = tid & 3;
  uint4 kp0 = *(const uint4*)(ktb + (size_t)row * CD + seg * 16);
  uint4 kp1 = *(const uint4*)(ktb + (size_t)row * CD + seg * 16 + 8);
  uint4 vp0 = *(const uint4*)(vnb + (size_t)row * STOT + seg * 16);
  uint4 vp1 = *(const uint4*)(vnb + (size_t)row * STOT + seg * 16 + 8);
  *(uint4*)&Kb[0][row * LDS_P + seg * 16]     = kp0;
  *(uint4*)&Kb[0][row * LDS_P + seg * 16 + 8] = kp1;
  *(uint4*)&Vb[0][row * LDS_P + seg * 16]     = vp0;
  *(uint4*)&Vb[0][row * LDS_P + seg * 16 + 8] = vp1;
  __syncthreads();
  f32x4 ofrag[4];
#pragma unroll
  for (int mt = 0; mt < 4; ++mt) ofrag[mt] = f32x4{0.f, 0.f, 0.f, 0.f};
  float l_acc = 0.f;
  for (int it = 0; it < NIT; ++it) {
    const int cur = it & 1;
    if (it + 1 < NIT) {
      const int s1 = (it + 1) * SK;
      kp0 = *(const uint4*)(ktb + ((size_t)(s1 + row)) * CD + seg * 16);
      kp1 = *(const uint4*)(ktb + ((size_t)(s1 + row)) * CD + seg * 16 + 8);
      vp0 = *(const uint4*)(vnb + (size_t)row * STOT + s1 + seg * 16);
      vp1 = *(const uint4*)(vnb + (size_t)row * STOT + s1 + seg * 16 + 8);
    }
    float ps[4][4];
#pragma unroll
    for (int mt = 0; mt < 4; ++mt) {
      f32x4 acc = f32x4{0.f, 0.f, 0.f, 0.f};
#pragma unroll
      for (int kst = 0; kst < 2; ++kst) {
        bf16x8 afr = *(const bf16x8*)&Kb[cur][(mt * 16 + l16) * LDS_P + kst * 32 + quad * 8];
        acc = __builtin_amdgcn_mfma_f32_16x16x32_bf16(afr, qfrag[kst], acc, 0, 0, 0);
      }
#pragma unroll
      for (int r = 0; r < 4; ++r) ps[mt][r] = acc[r];
    }
    ushort* pws = &Pw[w * 16 * LDS_P];
#pragma unroll
    for (int mt = 0; mt < 4; ++mt) {
      float p0 = exp2f(ps[mt][0] - M2);
      float p1 = exp2f(ps[mt][1] - M2);
      float p2 = exp2f(ps[mt][2] - M2);
      float p3 = exp2f(ps[mt][3] - M2);
      l_acc += (p0 + p1) + (p2 + p3);
      *(uint2*)&pws[l16 * LDS_P + mt * 16 + quad * 4] =
          make_uint2(pkbf(p0, p1), pkbf(p2, p3));
    }
    __asm__ __volatile__("s_waitcnt lgkmcnt(0)" ::: "memory");
    bf16x8 pfr[2];
#pragma unroll
    for (int kst = 0; kst < 2; ++kst)
      pfr[kst] = *(const bf16x8*)&Pw[(w * 16 + l16) * LDS_P + kst * 32 + quad * 8];
#pragma unroll
    for (int mt = 0; mt < 4; ++mt) {
#pragma unroll
      for (int kst = 0; kst < 2; ++kst) {
        bf16x8 vfr = *(const bf16x8*)&Vb[cur][(mt * 16 + l16) * LDS_P + kst * 32 + quad * 8];
        ofrag[mt] = __builtin_amdgcn_mfma_f32_16x16x32_bf16(vfr, pfr[kst], ofrag[mt], 0, 0, 0);
      }
    }
    if (it + 1 < NIT) {
      *(uint4*)&Kb[1 - cur][row * LDS_P + seg * 16]     = kp0;
      *(uint4*)&Kb[1 - cur][row * LDS_P + seg * 16 + 8] = kp1;
      *(uint4*)&Vb[1 - cur][row * LDS_P + seg * 16]     = vp0;
      *(uint4*)&Vb[1 - cur][row * LDS_P + seg * 16 + 8] = vp1;
      __syncthreads();
    }
  }
  {
    float lv = l_acc;
    lv += __shfl_xor(lv, 16);
    lv += __shfl_xor(lv, 32);
    float inv = 1.0f / lv;
#pragma unroll
    for (int mt = 0; mt < 4; ++mt) {
#pragma unroll
      for (int r = 0; r < 4; ++r) {
        int ci = mt * 16 + quad * 4 + r;
        og[ci * TLEN + t0 + w * 16 + l16] = ofrag[mt][r] * inv;
      }
    }
  }
}

extern "C" void kernel_launch(void* const* d_in, const int* in_sizes, int n_in,
                              void* d_out, int out_size, void* d_ws, size_t ws_size,
                              hipStream_t stream) {
  const float* x   = (const float*)d_in[0];   // (4, 1536, 1024) fp32
  const float* ekv = (const float*)d_in[1];   // (4, 1024, 1024) fp32
  float* out = (float*)d_out;                 // (4, 512, 1024) fp32
  ushort* ktw = (ushort*)d_ws;                             // 8.39 MB
  ushort* vnw = ktw + (size_t)32 * STOT * CD;              // 8.39 MB
  float*  pl  = (float*)(vnw + (size_t)32 * STOT * CD);    // 128 KB
  const size_t need_split = (size_t)32 * STOT * CD * 2 * 2 + (size_t)32 * TLEN * 4;
  repack_kernel<<<dim3(32, 32, 2), 256, 0, stream>>>(x, ekv, ktw, vnw);
  if (ws_size >= need_split) {
    hipMemsetAsync(out, 0, (size_t)out_size * 4, stream);
    hipMemsetAsync(pl, 0, (size_t)32 * TLEN * 4, stream);
    qkv_attn_split<<<1024, 256, 0, stream>>>(x, ktw, vnw, out, pl);
    finalize_kernel<<<2048, 256, 0, stream>>>(out, pl);
  } else {
    qkv_attn_ws<<<512, 256, 0, stream>>>(x, ktw, vnw, out);
  }
}

// Round 11
// 134.366 us; speedup vs baseline: 1.2384x; 1.2384x over previous
//
#include <hip/hip_runtime.h>

typedef __attribute__((ext_vector_type(8))) short bf16x8;
typedef __attribute__((ext_vector_type(4))) float f32x4;
typedef __attribute__((ext_vector_type(16))) float f32x16;

#define NH 8
#define CD 64
#define TLEN 1024
#define SENC 1024
#define STOT 2048
#define SK 64
#define LDS_P 72     // padded LDS row stride (bf16); 144B rows stay 16B-aligned

// fixed softmax max (mathematically exact for any fixed M; only float range)
#define QSCALE 0.18033688f   // 0.125 * log2(e)
#define M2     12.98425550f  // 9.0  * log2(e)

__device__ __forceinline__ ushort f2bf(float f) {
  uint x = __builtin_bit_cast(uint, f);
  uint r = (x + 0x7fffu + ((x >> 16) & 1u)) >> 16;
  return (ushort)r;
}
__device__ __forceinline__ uint pkbf(float a, float b) {
  return (uint)f2bf(a) | ((uint)f2bf(b) << 16);
}
__device__ __forceinline__ uint4 pack8(const ushort* p) {
  uint4 u;
  u.x = (uint)p[0] | ((uint)p[1] << 16);
  u.y = (uint)p[2] | ((uint)p[3] << 16);
  u.z = (uint)p[4] | ((uint)p[5] << 16);
  u.w = (uint)p[6] | ((uint)p[7] << 16);
  return u;
}

// ---------------- pre-pass: cast K/V to bf16 in workspace (R8-verified) -----
__global__ __launch_bounds__(256)
void repack_kernel(const float* __restrict__ x, const float* __restrict__ ekv,
                   ushort* __restrict__ ktw, ushort* __restrict__ vnw) {
  const int kx = blockIdx.x;   // key tile 0..31 (64 keys each)
  const int bh = blockIdx.y;   // 0..31
  const int b = bh >> 3, h = bh & 7;
  const int t = threadIdx.x;
  const float* ks;
  const float* vs;
  if (kx < 16) {
    ks = ekv + (size_t)(b * 2 * NH * CD + h * CD) * SENC + kx * 64;
    vs = ekv + (size_t)(b * 2 * NH * CD + NH * CD + h * CD) * SENC + kx * 64;
  } else {
    ks = x + (size_t)(b * 3 * NH * CD + NH * CD + h * CD) * TLEN + (kx - 16) * 64;
    vs = x + (size_t)(b * 3 * NH * CD + 2 * NH * CD + h * CD) * TLEN + (kx - 16) * 64;
  }
  if (blockIdx.z == 0) {
    __shared__ float Lt[64 * 65];
    const int ci = t >> 2, seg = t & 3;
#pragma unroll
    for (int j = 0; j < 4; ++j) {
      float4 d = *(const float4*)&ks[ci * 1024 + seg * 16 + 4 * j];
      Lt[ci * 65 + seg * 16 + 4 * j + 0] = d.x;
      Lt[ci * 65 + seg * 16 + 4 * j + 1] = d.y;
      Lt[ci * 65 + seg * 16 + 4 * j + 2] = d.z;
      Lt[ci * 65 + seg * 16 + 4 * j + 3] = d.w;
    }
    __syncthreads();
    const int key = t >> 2;
    ushort tmp[16];
#pragma unroll
    for (int u = 0; u < 16; ++u)
      tmp[u] = f2bf(Lt[(seg * 16 + u) * 65 + key]);
    ushort* dst = ktw + ((size_t)bh * STOT + kx * 64 + key) * CD + seg * 16;
    *(uint4*)dst = pack8(tmp);
    *(uint4*)(dst + 8) = pack8(tmp + 8);
  } else {
    const int ci = t >> 2, seg = t & 3;
    ushort tmp[16];
#pragma unroll
    for (int j = 0; j < 4; ++j) {
      float4 d = *(const float4*)&vs[ci * 1024 + seg * 16 + 4 * j];
      tmp[4 * j + 0] = f2bf(d.x);
      tmp[4 * j + 1] = f2bf(d.y);
      tmp[4 * j + 2] = f2bf(d.z);
      tmp[4 * j + 3] = f2bf(d.w);
    }
    ushort* dst = vnw + (size_t)bh * CD * STOT + (size_t)ci * STOT + kx * 64 + seg * 16;
    *(uint4*)dst = pack8(tmp);
    *(uint4*)(dst + 8) = pack8(tmp + 8);
  }
}

// ---------------- main: 32x32 MFMA + LDS-staged K/V dbuf + key-split 2 ------
// Wave = 32 queries x 64 keys/iter (R10-verified 32x32 fragment machinery on
// R9-verified staging/double-buffer skeleton). Fixed-max softmax => split
// partials are directly addable (atomic O/l epilogue + finalize divide).
__global__ __launch_bounds__(256, 2)
void qkv_attn_split(const float* __restrict__ x, const ushort* __restrict__ ktw,
                    const ushort* __restrict__ vnw, float* __restrict__ out,
                    float* __restrict__ pl) {
  __shared__ __align__(16) ushort Kb[2][SK * LDS_P];   // [buf][key][ci]
  __shared__ __align__(16) ushort Vb[2][CD * LDS_P];   // [buf][ci][key]
  __shared__ __align__(16) ushort Pw[4][32 * LDS_P];   // per-wave P^T[q32][key64]

  const int tid  = threadIdx.x;
  const int w    = tid >> 6;
  const int lane = tid & 63;
  const int hi   = lane >> 5;
  const int l32  = lane & 31;

  // XCD swizzle: all 16 blocks of one bh land on XCD f%8 = bh&7
  const int f   = blockIdx.x;
  const int bh  = (f & 7) + 8 * (f >> 7);
  const int mid = (f >> 3) & 15;
  const int qg  = mid >> 1;       // 0..7 : 128-query group
  const int sp  = mid & 1;        // 0..1 : 1024-key split
  const int b = bh >> 3, h = bh & 7;
  const int q0  = qg * 128 + w * 32;   // this wave's query base
  const int s0b = sp * 1024;

  const float* qgp = x + (size_t)(b * 3 * NH * CD + h * CD) * TLEN;
  const ushort* ktb = ktw + (size_t)bh * STOT * CD;   // [key][ci]
  const ushort* vnb = vnw + (size_t)bh * CD * STOT;   // [ci][key]
  float* og = out + (size_t)(b * NH * CD + h * CD) * TLEN;

  // ---- Q B-frags (hoisted): B[k=ci=kt*16+hi*8+j][n=q0+l32]  (R10-verified)
  bf16x8 qf[4];
#pragma unroll
  for (int kt = 0; kt < 4; ++kt) {
    const float* qc = qgp + (size_t)(kt * 16 + hi * 8) * TLEN + q0 + l32;
    float a0 = qc[0 * TLEN] * QSCALE, a1 = qc[1 * TLEN] * QSCALE;
    float a2 = qc[2 * TLEN] * QSCALE, a3 = qc[3 * TLEN] * QSCALE;
    float a4 = qc[4 * TLEN] * QSCALE, a5 = qc[5 * TLEN] * QSCALE;
    float a6 = qc[6 * TLEN] * QSCALE, a7 = qc[7 * TLEN] * QSCALE;
    qf[kt] = __builtin_bit_cast(bf16x8,
        make_uint4(pkbf(a0, a1), pkbf(a2, a3), pkbf(a4, a5), pkbf(a6, a7)));
  }

  // ---- prefetch chunk 0 into regs, stage into buf 0 (R9-verified pattern)
  const int row = tid >> 2, seg = tid & 3;
  uint4 kp0 = *(const uint4*)(ktb + (size_t)(s0b + row) * CD + seg * 16);
  uint4 kp1 = *(const uint4*)(ktb + (size_t)(s0b + row) * CD + seg * 16 + 8);
  uint4 vp0 = *(const uint4*)(vnb + (size_t)row * STOT + s0b + seg * 16);
  uint4 vp1 = *(const uint4*)(vnb + (size_t)row * STOT + s0b + seg * 16 + 8);
  *(uint4*)&Kb[0][row * LDS_P + seg * 16]     = kp0;
  *(uint4*)&Kb[0][row * LDS_P + seg * 16 + 8] = kp1;
  *(uint4*)&Vb[0][row * LDS_P + seg * 16]     = vp0;
  *(uint4*)&Vb[0][row * LDS_P + seg * 16 + 8] = vp1;
  __syncthreads();

  f32x16 oa0 = {0,0,0,0,0,0,0,0,0,0,0,0,0,0,0,0};
  f32x16 oa1 = {0,0,0,0,0,0,0,0,0,0,0,0,0,0,0,0};
  float l_acc = 0.f;
  ushort* pws = &Pw[w][l32 * LDS_P];   // this lane's P^T row (q = l32)

  for (int it = 0; it < 16; ++it) {
    const int cur = it & 1;

    // ---- issue next chunk's global loads first (overlap with compute)
    if (it + 1 < 16) {
      const int s1 = s0b + (it + 1) * SK;
      kp0 = *(const uint4*)(ktb + (size_t)(s1 + row) * CD + seg * 16);
      kp1 = *(const uint4*)(ktb + (size_t)(s1 + row) * CD + seg * 16 + 8);
      vp0 = *(const uint4*)(vnb + (size_t)row * STOT + s1 + seg * 16);
      vp1 = *(const uint4*)(vnb + (size_t)row * STOT + s1 + seg * 16 + 8);
    }

    // ---- S^T = K*Q^T : A[m=key=mt*32+l32][k=ci=kt*16+hi*8+j] from Kb
    f32x16 st0 = {0,0,0,0,0,0,0,0,0,0,0,0,0,0,0,0};
    f32x16 st1 = {0,0,0,0,0,0,0,0,0,0,0,0,0,0,0,0};
#pragma unroll
    for (int kt = 0; kt < 4; ++kt) {
      bf16x8 a0f = *(const bf16x8*)&Kb[cur][(l32)      * LDS_P + kt * 16 + hi * 8];
      bf16x8 a1f = *(const bf16x8*)&Kb[cur][(32 + l32) * LDS_P + kt * 16 + hi * 8];
      st0 = __builtin_amdgcn_mfma_f32_32x32x16_bf16(a0f, qf[kt], st0, 0, 0, 0);
      st1 = __builtin_amdgcn_mfma_f32_32x32x16_bf16(a1f, qf[kt], st1, 0, 0, 0);
    }

    // ---- fixed-max softmax + P^T write (wave-private rows; R10-verified)
    // C layout: col = q = l32, key_local = mt*32 + (r&3) + 8*(r>>2) + 4*hi
#pragma unroll
    for (int mt = 0; mt < 2; ++mt) {
      const f32x16 st = mt ? st1 : st0;
      float p[16];
#pragma unroll
      for (int r = 0; r < 16; ++r) {
        p[r] = exp2f(st[r] - M2);
        l_acc += p[r];
      }
#pragma unroll
      for (int g = 0; g < 4; ++g) {
        *(uint2*)&pws[mt * 32 + 8 * g + 4 * hi] =
            make_uint2(pkbf(p[4 * g + 0], p[4 * g + 1]),
                       pkbf(p[4 * g + 2], p[4 * g + 3]));
      }
    }
    __asm__ __volatile__("s_waitcnt lgkmcnt(0)" ::: "memory");

    // ---- P^T B-frags (own row) + O^T += V * P^T  (V from Vb)
#pragma unroll
    for (int kt2 = 0; kt2 < 4; ++kt2) {
      bf16x8 pfr = *(const bf16x8*)&pws[kt2 * 16 + hi * 8];
      bf16x8 v0f = *(const bf16x8*)&Vb[cur][(l32)      * LDS_P + kt2 * 16 + hi * 8];
      bf16x8 v1f = *(const bf16x8*)&Vb[cur][(32 + l32) * LDS_P + kt2 * 16 + hi * 8];
      oa0 = __builtin_amdgcn_mfma_f32_32x32x16_bf16(v0f, pfr, oa0, 0, 0, 0);
      oa1 = __builtin_amdgcn_mfma_f32_32x32x16_bf16(v1f, pfr, oa1, 0, 0, 0);
    }

    // ---- stage prefetched chunk; single barrier per iter
    if (it + 1 < 16) {
      *(uint4*)&Kb[1 - cur][row * LDS_P + seg * 16]     = kp0;
      *(uint4*)&Kb[1 - cur][row * LDS_P + seg * 16 + 8] = kp1;
      *(uint4*)&Vb[1 - cur][row * LDS_P + seg * 16]     = vp0;
      *(uint4*)&Vb[1 - cur][row * LDS_P + seg * 16 + 8] = vp1;
      __syncthreads();
    }
  }

  // ---- epilogue: accumulate split partials (fixed-max => addable)
  l_acc += __shfl_xor(l_acc, 32);   // combine hi-halves for query l32
  if (hi == 0) atomicAdd(&pl[bh * TLEN + q0 + l32], l_acc);
#pragma unroll
  for (int mt2 = 0; mt2 < 2; ++mt2) {
    const f32x16 oa = mt2 ? oa1 : oa0;
#pragma unroll
    for (int r = 0; r < 16; ++r) {
      int ci = mt2 * 32 + (r & 3) + 8 * (r >> 2) + 4 * hi;
      atomicAdd(&og[(size_t)ci * TLEN + q0 + l32], oa[r]);
    }
  }
}

// ---------------- finalize: out /= l ----------------------------------------
__global__ __launch_bounds__(256)
void finalize_kernel(float* __restrict__ out, const float* __restrict__ pl) {
  int i = blockIdx.x * 256 + threadIdx.x;      // float4 index, 524288 total
  float4 v = ((const float4*)out)[i];
  int flat = i * 4;
  int bh = flat >> 16;                         // 64*1024 floats per bh
  int t  = flat & 1023;
  const float4 lv = *(const float4*)&pl[bh * 1024 + t];
  v.x /= lv.x; v.y /= lv.y; v.z /= lv.z; v.w /= lv.w;
  ((float4*)out)[i] = v;
}

// ---------------- R9 fallback (verified 54.7 us) for small workspace --------
#define BQ 64
#define NIT (STOT / SK)
__global__ __launch_bounds__(256, 3)
void qkv_attn_ws(const float* __restrict__ x, const ushort* __restrict__ ktw,
                 const ushort* __restrict__ vnw, float* __restrict__ out) {
  __shared__ __align__(16) ushort Kb[2][SK * LDS_P];
  __shared__ __align__(16) ushort Vb[2][CD * LDS_P];
  __shared__ __align__(16) ushort Pw[4 * 16 * LDS_P];
  const int tid = threadIdx.x, w = tid >> 6, lane = tid & 63;
  const int quad = lane >> 4, l16 = lane & 15;
  const int f = blockIdx.x;
  const int bh = (f & 7) + 8 * (f >> 7);
  const int qt = (f >> 3) & 15;
  const int b = bh >> 3, h = bh & 7, t0 = qt * BQ;
  const float* qg = x + (size_t)(b * 3 * NH * CD + h * CD) * TLEN;
  float* og = out + (size_t)(b * NH * CD + h * CD) * TLEN;
  const ushort* ktb = ktw + (size_t)bh * STOT * CD;
  const ushort* vnb = vnw + (size_t)bh * CD * STOT;
#pragma unroll
  for (int e = 0; e < 16; ++e) {
    int ci = 4 * e + w;
    Kb[1][lane * LDS_P + ci] = f2bf(qg[ci * TLEN + t0 + lane] * QSCALE);
  }
  __syncthreads();
  bf16x8 qfrag[2];
#pragma unroll
  for (int kst = 0; kst < 2; ++kst)
    qfrag[kst] = *(const bf16x8*)&Kb[1][(w * 16 + l16) * LDS_P + kst * 32 + quad * 8];
  const int row = tid >> 2, seg = tid & 3;
  uint4 kp0 = *(const uint4*)(ktb + (size_t)row * CD + seg * 16);
  uint4 kp1 = *(const uint4*)(ktb + (size_t)row * CD + seg * 16 + 8);
  uint4 vp0 = *(const uint4*)(vnb + (size_t)row * STOT + seg * 16);
  uint4 vp1 = *(const uint4*)(vnb + (size_t)row * STOT + seg * 16 + 8);
  *(uint4*)&Kb[0][row * LDS_P + seg * 16]     = kp0;
  *(uint4*)&Kb[0][row * LDS_P + seg * 16 + 8] = kp1;
  *(uint4*)&Vb[0][row * LDS_P + seg * 16]     = vp0;
  *(uint4*)&Vb[0][row * LDS_P + seg * 16 + 8] = vp1;
  __syncthreads();
  f32x4 ofrag[4];
#pragma unroll
  for (int mt = 0; mt < 4; ++mt) ofrag[mt] = f32x4{0.f, 0.f, 0.f, 0.f};
  float l_acc = 0.f;
  for (int it = 0; it < NIT; ++it) {
    const int cur = it & 1;
    if (it + 1 < NIT) {
      const int s1 = (it + 1) * SK;
      kp0 = *(const uint4*)(ktb + ((size_t)(s1 + row)) * CD + seg * 16);
      kp1 = *(const uint4*)(ktb + ((size_t)(s1 + row)) * CD + seg * 16 + 8);
      vp0 = *(const uint4*)(vnb + (size_t)row * STOT + s1 + seg * 16);
      vp1 = *(const uint4*)(vnb + (size_t)row * STOT + s1 + seg * 16 + 8);
    }
    float ps[4][4];
#pragma unroll
    for (int mt = 0; mt < 4; ++mt) {
      f32x4 acc = f32x4{0.f, 0.f, 0.f, 0.f};
#pragma unroll
      for (int kst = 0; kst < 2; ++kst) {
        bf16x8 afr = *(const bf16x8*)&Kb[cur][(mt * 16 + l16) * LDS_P + kst * 32 + quad * 8];
        acc = __builtin_amdgcn_mfma_f32_16x16x32_bf16(afr, qfrag[kst], acc, 0, 0, 0);
      }
#pragma unroll
      for (int r = 0; r < 4; ++r) ps[mt][r] = acc[r];
    }
    ushort* pws = &Pw[w * 16 * LDS_P];
#pragma unroll
    for (int mt = 0; mt < 4; ++mt) {
      float p0 = exp2f(ps[mt][0] - M2);
      float p1 = exp2f(ps[mt][1] - M2);
      float p2 = exp2f(ps[mt][2] - M2);
      float p3 = exp2f(ps[mt][3] - M2);
      l_acc += (p0 + p1) + (p2 + p3);
      *(uint2*)&pws[l16 * LDS_P + mt * 16 + quad * 4] =
          make_uint2(pkbf(p0, p1), pkbf(p2, p3));
    }
    __asm__ __volatile__("s_waitcnt lgkmcnt(0)" ::: "memory");
    bf16x8 pfr[2];
#pragma unroll
    for (int kst = 0; kst < 2; ++kst)
      pfr[kst] = *(const bf16x8*)&Pw[(w * 16 + l16) * LDS_P + kst * 32 + quad * 8];
#pragma unroll
    for (int mt = 0; mt < 4; ++mt) {
#pragma unroll
      for (int kst = 0; kst < 2; ++kst) {
        bf16x8 vfr = *(const bf16x8*)&Vb[cur][(mt * 16 + l16) * LDS_P + kst * 32 + quad * 8];
        ofrag[mt] = __builtin_amdgcn_mfma_f32_16x16x32_bf16(vfr, pfr[kst], ofrag[mt], 0, 0, 0);
      }
    }
    if (it + 1 < NIT) {
      *(uint4*)&Kb[1 - cur][row * LDS_P + seg * 16]     = kp0;
      *(uint4*)&Kb[1 - cur][row * LDS_P + seg * 16 + 8] = kp1;
      *(uint4*)&Vb[1 - cur][row * LDS_P + seg * 16]     = vp0;
      *(uint4*)&Vb[1 - cur][row * LDS_P + seg * 16 + 8] = vp1;
      __syncthreads();
    }
  }
  {
    float lv = l_acc;
    lv += __shfl_xor(lv, 16);
    lv += __shfl_xor(lv, 32);
    float inv = 1.0f / lv;
#pragma unroll
    for (int mt = 0; mt < 4; ++mt) {
#pragma unroll
      for (int r = 0; r < 4; ++r) {
        int ci = mt * 16 + quad * 4 + r;
        og[ci * TLEN + t0 + w * 16 + l16] = ofrag[mt][r] * inv;
      }
    }
  }
}

extern "C" void kernel_launch(void* const* d_in, const int* in_sizes, int n_in,
                              void* d_out, int out_size, void* d_ws, size_t ws_size,
                              hipStream_t stream) {
  const float* x   = (const float*)d_in[0];   // (4, 1536, 1024) fp32
  const float* ekv = (const float*)d_in[1];   // (4, 1024, 1024) fp32
  float* out = (float*)d_out;                 // (4, 512, 1024) fp32
  ushort* ktw = (ushort*)d_ws;                             // 8.39 MB
  ushort* vnw = ktw + (size_t)32 * STOT * CD;              // 8.39 MB
  float*  pl  = (float*)(vnw + (size_t)32 * STOT * CD);    // 128 KB
  const size_t need_split = (size_t)32 * STOT * CD * 2 * 2 + (size_t)32 * TLEN * 4;
  repack_kernel<<<dim3(32, 32, 2), 256, 0, stream>>>(x, ekv, ktw, vnw);
  if (ws_size >= need_split) {
    hipMemsetAsync(out, 0, (size_t)out_size * 4, stream);
    hipMemsetAsync(pl, 0, (size_t)32 * TLEN * 4, stream);
    qkv_attn_split<<<512, 256, 0, stream>>>(x, ktw, vnw, out, pl);
    finalize_kernel<<<2048, 256, 0, stream>>>(out, pl);
  } else {
    qkv_attn_ws<<<512, 256, 0, stream>>>(x, ktw, vnw, out);
  }
}